// Round 5
// baseline (5284.224 us; speedup 1.0000x reference)
//
#include <hip/hip_runtime.h>

#define B_   64
#define T_   512
#define D_   512
#define H_   1024
#define G4   4096      // 4*H
#define KC_N 48        // (D+H)/32 k-chunks

typedef float f32x4 __attribute__((ext_vector_type(4)));
typedef short s16x8 __attribute__((ext_vector_type(8)));

__device__ __forceinline__ unsigned short f2bf(float f) {
    unsigned int u = __float_as_uint(f);
    u = (u + 0x7fffu + ((u >> 16) & 1u)) >> 16;   // RNE
    return (unsigned short)u;
}
__device__ __forceinline__ float sigm(float x) { return 1.f / (1.f + __expf(-x)); }
__device__ __forceinline__ float tanh_f(float x) { return 1.f - 2.f / (__expf(2.f * x) + 1.f); }

// 8x f32 -> 8x bf16 (RNE) via v_cvt_pk_bf16_f32 (lo = src0)
__device__ __forceinline__ s16x8 cvt8(float4 a, float4 b) {
    union { s16x8 v; unsigned int u[4]; } r;
    asm("v_cvt_pk_bf16_f32 %0, %1, %2" : "=v"(r.u[0]) : "v"(a.x), "v"(a.y));
    asm("v_cvt_pk_bf16_f32 %0, %1, %2" : "=v"(r.u[1]) : "v"(a.z), "v"(a.w));
    asm("v_cvt_pk_bf16_f32 %0, %1, %2" : "=v"(r.u[2]) : "v"(b.x), "v"(b.y));
    asm("v_cvt_pk_bf16_f32 %0, %1, %2" : "=v"(r.u[3]) : "v"(b.z), "v"(b.w));
    return r.v;
}

// Pack [W_ih | W_hh] into exact MFMA B-fragment order, bf16, gate-interleaved
// columns (packed col n = 4*j_hidden + gate):
// Wpk[(((c*48 + kc)*64 + lane))*8 + j] = W[row(n)][k], n = c*16 + (lane&15),
// k = kc*32 + (lane>>4)*8 + j.
__global__ __launch_bounds__(256) void pack_w(const float* __restrict__ W_ih,
                                              const float* __restrict__ W_hh,
                                              unsigned short* __restrict__ Wpk) {
    int tid = blockIdx.x * 256 + threadIdx.x;        // [0, 256*48*64*8)
    int j    = tid & 7;
    int lane = (tid >> 3) & 63;
    int rest = tid >> 9;
    int kc = rest % KC_N;
    int c  = rest / KC_N;
    int npk = c * 16 + (lane & 15);
    int jh = npk >> 2, g = npk & 3;
    int row = g * H_ + jh;                           // torch gate order i,f,g,o
    int k = kc * 32 + (lane >> 4) * 8 + j;
    float v = (k < D_) ? W_ih[row * D_ + k] : W_hh[row * H_ + (k - D_)];
    Wpk[tid] = f2bf(v);
}

// h buffer: 2 parities x [64 rows][1024 units] of f32 words
// word = (bf16(h) << 16) | (step_tag & 0xffff).  Init: h0 with tag 0.
__global__ __launch_bounds__(256) void init_state2(
    const float* __restrict__ h0, const float* __restrict__ b_ih,
    const float* __restrict__ b_hh, unsigned int* __restrict__ hbuf32,
    float* __restrict__ bias_p)
{
    int tid = blockIdx.x * 256 + threadIdx.x;        // 131072 threads
    int j = tid & (H_ - 1);
    hbuf32[tid] = ((unsigned int)f2bf(h0[j]) << 16); // tag 0 both parities
    if (tid < G4) {                                  // bias in packed-col order
        int jh = tid >> 2, g = tid & 3;
        bias_p[tid] = b_ih[g * H_ + jh] + b_hh[g * H_ + jh];
    }
}

// Persistent LSTM: 256 blocks (1/CU), 512 threads (8 waves).
// block = (colgroup cg: 32 packed cols = 8 hidden units) x (batch half mh: 32 rows)
// wave  = (mi: 16-row m-tile) x (ks: k-slice = 4 x-kc + 8 h-kc)
// Weights pinned in VGPR/AGPR (empty-asm keep-alive).
// Sync: NO flags, NO drain, NO block barrier for release. Each h word carries
// its step tag; each wave polls ITS OWN slice until all 64 tags match, and the
// successful poll already holds the data (1.5-2 LLC RTs vs 3.5 for flag scheme).
__global__ __launch_bounds__(512) void lstm_persist(
    const float* __restrict__ x, const int* __restrict__ mask,
    const unsigned short* __restrict__ Wpk, const float* __restrict__ bias_p,
    const float* __restrict__ h0, const float* __restrict__ c0,
    unsigned int* __restrict__ hbuf32, float* __restrict__ out)
{
    const int tid = threadIdx.x;
    const int bid = blockIdx.x;
    const int cg  = bid >> 1;            // 0..127 colgroup
    const int mh  = bid & 1;             // batch half
    const int b0g = mh << 5;

    const int w = tid >> 6, l = tid & 63;
    const int quad = l >> 4, l15 = l & 15;
    const int mi = w >> 2;               // 0..1
    const int ks = w & 3;                // 0..3
    const int arow = b0g + mi * 16 + l15;

    __shared__ float Dls[4][32][36];     // [ks][m-row][gate-col], padded

    // ---- pinned B fragments: wave's 12 kc = {ks*4+0..3 (x), 16+ks*8+0..7 (h)} ----
    s16x8 Bf0[12], Bf1[12];
    {
        const unsigned short* base0 = Wpk + (size_t)((cg * 2 + 0) * KC_N) * 512;
        const unsigned short* base1 = Wpk + (size_t)((cg * 2 + 1) * KC_N) * 512;
        #pragma unroll
        for (int i = 0; i < 12; ++i) {
            int kc = (i < 4) ? (ks * 4 + i) : (16 + ks * 8 + (i - 4));
            Bf0[i] = *reinterpret_cast<const s16x8*>(base0 + ((size_t)kc * 64 + l) * 8);
            Bf1[i] = *reinterpret_cast<const s16x8*>(base1 + ((size_t)kc * 64 + l) * 8);
        }
        #pragma unroll
        for (int i = 0; i < 12; ++i)
            asm volatile("" : "+v"(Bf0[i]), "+v"(Bf1[i]));   // liveness pin
    }

    // ---- epilogue thread state (tid<256): thread -> (batch b_l, hidden unit u) ----
    const int b_l = tid >> 3, u = tid & 7;
    const int brow = b0g + b_l;
    const int jcol = cg * 8 + u;
    float c_reg = 0.f, h_reg = 0.f;
    float4 bias = make_float4(0.f, 0.f, 0.f, 0.f);
    if (tid < 256) {
        c_reg = c0[jcol];
        h_reg = h0[jcol];
        bias = *reinterpret_cast<const float4*>(bias_p + cg * 32 + u * 4);
    }

    const float* xbase = x + (size_t)arow * T_ * D_ + ks * 128 + quad * 8;

    #pragma unroll 1
    for (int t = 0; t < T_; ++t) {
        const unsigned int* hin32  = hbuf32 + (size_t)(t & 1) * (B_ * H_);
        unsigned int*       hout32 = hbuf32 + (size_t)((t + 1) & 1) * (B_ * H_);

        // ---- phase A: x-part MFMA (no h dependency) + mask prefetch ----
        f32x4 a0 = {0.f, 0.f, 0.f, 0.f}, a1 = {0.f, 0.f, 0.f, 0.f};
        const float* xp = xbase + (size_t)t * D_;
        int mv = 0;
        if (tid < 256) mv = mask[(size_t)brow * T_ + t];
        #pragma unroll
        for (int i = 0; i < 4; ++i) {
            float4 v0 = *reinterpret_cast<const float4*>(xp + i * 32);
            float4 v1 = *reinterpret_cast<const float4*>(xp + i * 32 + 4);
            s16x8 af = cvt8(v0, v1);
            a0 = __builtin_amdgcn_mfma_f32_16x16x32_bf16(af, Bf0[i], a0, 0, 0, 0);
            a1 = __builtin_amdgcn_mfma_f32_16x16x32_bf16(af, Bf1[i], a1, 0, 0, 0);
        }

        // ---- phase B: poll tagged h words — the data IS the flag ----
        // wave's slice: rows arow, h indices ks*256 + i*32 + quad*8 + j (i<8,j<8)
        const unsigned int* hrowf = hin32 + (size_t)arow * H_ + ks * 256 + quad * 8;
        const unsigned int tag = (unsigned int)t & 0xffffu;
        s16x8 hf[8];
        {
            int guard = 0;
            for (;;) {
                unsigned long long q[32];
                #pragma unroll
                for (int i = 0; i < 8; ++i) {
                    const unsigned long long* p =
                        reinterpret_cast<const unsigned long long*>(hrowf + i * 32);
                    q[i*4+0] = __hip_atomic_load(p+0, __ATOMIC_RELAXED, __HIP_MEMORY_SCOPE_AGENT);
                    q[i*4+1] = __hip_atomic_load(p+1, __ATOMIC_RELAXED, __HIP_MEMORY_SCOPE_AGENT);
                    q[i*4+2] = __hip_atomic_load(p+2, __ATOMIC_RELAXED, __HIP_MEMORY_SCOPE_AGENT);
                    q[i*4+3] = __hip_atomic_load(p+3, __ATOMIC_RELAXED, __HIP_MEMORY_SCOPE_AGENT);
                }
                int ok = 1;
                #pragma unroll
                for (int i = 0; i < 32; ++i)
                    ok &= (int)((((unsigned int)q[i] & 0xffffu) == tag) &
                                (((unsigned int)(q[i] >> 32) & 0xffffu) == tag));
                ++guard;
                if (__all(ok) || guard > 20000) {
                    // pack: word pair -> one dword of 2 bf16 (high halves)
                    #pragma unroll
                    for (int i = 0; i < 8; ++i) {
                        union { s16x8 v; unsigned int d[4]; } fu;
                        #pragma unroll
                        for (int d4 = 0; d4 < 4; ++d4) {
                            unsigned long long wq = q[i*4 + d4];
                            fu.d[d4] = ((unsigned int)(wq >> 32) & 0xffff0000u) |
                                       ((unsigned int)wq >> 16);
                        }
                        hf[i] = fu.v;
                    }
                    break;
                }
                __builtin_amdgcn_s_sleep(4);
            }
        }
        #pragma unroll
        for (int i = 0; i < 8; ++i) {
            a0 = __builtin_amdgcn_mfma_f32_16x16x32_bf16(hf[i], Bf0[4 + i], a0, 0, 0, 0);
            a1 = __builtin_amdgcn_mfma_f32_16x16x32_bf16(hf[i], Bf1[4 + i], a1, 0, 0, 0);
        }
        // C/D layout: col = lane&15, row = quad*4 + reg (m89-verified)
        #pragma unroll
        for (int r = 0; r < 4; ++r) {
            Dls[ks][mi * 16 + quad * 4 + r][l15]      = a0[r];
            Dls[ks][mi * 16 + quad * 4 + r][16 + l15] = a1[r];
        }
        __syncthreads();

        // ---- epilogue: reduce 4 k-slices, LSTM cell, tagged h store (sc1) ----
        if (tid < 256) {
            f32x4 s0 = *reinterpret_cast<f32x4*>(&Dls[0][b_l][u * 4]);
            f32x4 s1 = *reinterpret_cast<f32x4*>(&Dls[1][b_l][u * 4]);
            f32x4 s2 = *reinterpret_cast<f32x4*>(&Dls[2][b_l][u * 4]);
            f32x4 s3 = *reinterpret_cast<f32x4*>(&Dls[3][b_l][u * 4]);
            f32x4 g = s0 + s1 + s2 + s3;
            float gi = sigm  (g[0] + bias.x);
            float gf = sigm  (g[1] + bias.y);
            float gg = tanh_f(g[2] + bias.z);
            float go = sigm  (g[3] + bias.w);
            float c_new = gf * c_reg + gi * gg;
            float h_new = go * tanh_f(c_new);
            float h2 = mv ? h_new : h_reg;
            c_reg = mv ? c_new : c_reg;
            h_reg = h2;
            // tagged word: payload + step tag atomically in one dword
            if (t < T_ - 1) {
                unsigned int wv = ((unsigned int)f2bf(h2) << 16) |
                                  ((unsigned int)(t + 1) & 0xffffu);
                __hip_atomic_store(hout32 + (size_t)brow * H_ + jcol, wv,
                                   __ATOMIC_RELAXED, __HIP_MEMORY_SCOPE_AGENT);
            }
            out[((size_t)brow * T_ + t) * H_ + jcol] = h2;
        }
        __syncthreads();   // Dls reuse protection only (no drain semantics needed)
    }
}

extern "C" void kernel_launch(void* const* d_in, const int* in_sizes, int n_in,
                              void* d_out, int out_size, void* d_ws, size_t ws_size,
                              hipStream_t stream)
{
    const float* x    = (const float*)d_in[0];
    const int*   mask = (const int*)d_in[1];
    const float* W_ih = (const float*)d_in[2];
    const float* W_hh = (const float*)d_in[3];
    const float* b_ih = (const float*)d_in[4];
    const float* b_hh = (const float*)d_in[5];
    const float* h0   = (const float*)d_in[6];
    const float* c0   = (const float*)d_in[7];
    float* out = (float*)d_out;

    // ws layout (~13.1 MB total)
    char* wsb = (char*)d_ws;
    unsigned short* Wpk    = (unsigned short*)(wsb);             // 12,582,912 B
    float*          bias_p = (float*)(wsb + 12582912);           //     16,384 B
    unsigned int*   hbuf32 = (unsigned int*)(wsb + 12599296);    //    524,288 B (2 parities)

    // inputs re-poisoned every call -> re-pack every call
    pack_w<<<24576, 256, 0, stream>>>(W_ih, W_hh, Wpk);
    init_state2<<<512, 256, 0, stream>>>(h0, b_ih, b_hh, hbuf32, bias_p);
    lstm_persist<<<256, 512, 0, stream>>>(x, mask, Wpk, bias_p, h0, c0, hbuf32, out);
}

// Round 6
// 3881.440 us; speedup vs baseline: 1.3614x; 1.3614x over previous
//
#include <hip/hip_runtime.h>

#define B_   64
#define T_   512
#define D_   512
#define H_   1024
#define G4   4096      // 4*H
#define KC_N 48        // (D+H)/32 k-chunks

typedef float f32x4 __attribute__((ext_vector_type(4)));
typedef short s16x8 __attribute__((ext_vector_type(8)));

__device__ __forceinline__ unsigned short f2bf(float f) {
    unsigned int u = __float_as_uint(f);
    u = (u + 0x7fffu + ((u >> 16) & 1u)) >> 16;   // RNE
    return (unsigned short)u;
}
__device__ __forceinline__ float sigm(float x) { return 1.f / (1.f + __expf(-x)); }
__device__ __forceinline__ float tanh_f(float x) { return 1.f - 2.f / (__expf(2.f * x) + 1.f); }

// 8x f32 -> 8x bf16 (RNE) via v_cvt_pk_bf16_f32 (lo = src0)
__device__ __forceinline__ s16x8 cvt8(float4 a, float4 b) {
    union { s16x8 v; unsigned int u[4]; } r;
    asm("v_cvt_pk_bf16_f32 %0, %1, %2" : "=v"(r.u[0]) : "v"(a.x), "v"(a.y));
    asm("v_cvt_pk_bf16_f32 %0, %1, %2" : "=v"(r.u[1]) : "v"(a.z), "v"(a.w));
    asm("v_cvt_pk_bf16_f32 %0, %1, %2" : "=v"(r.u[2]) : "v"(b.x), "v"(b.y));
    asm("v_cvt_pk_bf16_f32 %0, %1, %2" : "=v"(r.u[3]) : "v"(b.z), "v"(b.w));
    return r.v;
}

// Pack [W_ih | W_hh] into exact MFMA B-fragment order, bf16, gate-interleaved
// columns (packed col n = 4*j_hidden + gate):
// Wpk[(((c*48 + kc)*64 + lane))*8 + j] = W[row(n)][k], n = c*16 + (lane&15),
// k = kc*32 + (lane>>4)*8 + j.
__global__ __launch_bounds__(256) void pack_w(const float* __restrict__ W_ih,
                                              const float* __restrict__ W_hh,
                                              unsigned short* __restrict__ Wpk) {
    int tid = blockIdx.x * 256 + threadIdx.x;        // [0, 256*48*64*8)
    int j    = tid & 7;
    int lane = (tid >> 3) & 63;
    int rest = tid >> 9;
    int kc = rest % KC_N;
    int c  = rest / KC_N;
    int npk = c * 16 + (lane & 15);
    int jh = npk >> 2, g = npk & 3;
    int row = g * H_ + jh;                           // torch gate order i,f,g,o
    int k = kc * 32 + (lane >> 4) * 8 + j;
    float v = (k < D_) ? W_ih[row * D_ + k] : W_hh[row * H_ + (k - D_)];
    Wpk[tid] = f2bf(v);
}

__global__ __launch_bounds__(256) void init_state2(
    const float* __restrict__ h0, const float* __restrict__ b_ih,
    const float* __restrict__ b_hh, unsigned short* __restrict__ hbuf,
    float* __restrict__ bias_p, unsigned int* __restrict__ flags)
{
    int tid = blockIdx.x * 256 + threadIdx.x;        // 65536 threads
    int j = tid & (H_ - 1);
    hbuf[tid]  = f2bf(h0[j]);                        // h buffer parity 0
    if (tid < G4) {                                  // bias in packed-col order
        int jh = tid >> 2, g = tid & 3;
        bias_p[tid] = b_ih[g * H_ + jh] + b_hh[g * H_ + jh];
    }
    if (tid < 1024) flags[tid] = 0u;                 // [mh][rowgrp 0..3][cg 0..127]
}

// Persistent LSTM: 256 blocks (1/CU), 512 threads (8 waves).
// block = (colgroup cg: 32 packed cols = 8 hidden units) x (batch half mh: 32 rows)
// wave  = (mi: 16-row m-tile) x (ks: k-slice = 4 x-kc + 8 h-kc)
// Weights pinned in VGPR/AGPR (empty-asm keep-alive).
// Sync (decentralized, per-wave): producer wave (rowgrp w<4, rows w*8..w*8+8)
// stores its h slice -> own-wave s_waitcnt vmcnt(0) -> stores flags[mh][w][cg].
// Consumer wave mi polls ONLY the 256 flags of rowgrps {2mi,2mi+1} (4 dwords/
// lane, thin 1KB/wave poll) then loads h directly. No s_barrier, no drain
// syncthreads. Transitivity: flag(t+1) from wave r of block P implies P passed
// its step-t __syncthreads, i.e. ALL P's waves read h(t-1) and Dls(t) already
// -> parity reuse and Dls overwrite are race-free with ONE syncthreads/step.
__global__ __launch_bounds__(512) void lstm_persist(
    const float* __restrict__ x, const int* __restrict__ mask,
    const unsigned short* __restrict__ Wpk, const float* __restrict__ bias_p,
    const float* __restrict__ h0, const float* __restrict__ c0,
    unsigned short* __restrict__ hbuf, float* __restrict__ out,
    unsigned int* __restrict__ flags)
{
    const int tid = threadIdx.x;
    const int bid = blockIdx.x;
    const int cg  = bid >> 1;            // 0..127 colgroup
    const int mh  = bid & 1;             // batch half
    const int b0g = mh << 5;

    const int w = tid >> 6, l = tid & 63;
    const int quad = l >> 4, l15 = l & 15;
    const int mi = w >> 2;               // 0..1
    const int ks = w & 3;                // 0..3
    const int arow = b0g + mi * 16 + l15;

    __shared__ float Dls[4][32][36];     // [ks][m-row][gate-col], padded

    // ---- pinned B fragments: wave's 12 kc = {ks*4+0..3 (x), 16+ks*8+0..7 (h)} ----
    s16x8 Bf0[12], Bf1[12];
    {
        const unsigned short* base0 = Wpk + (size_t)((cg * 2 + 0) * KC_N) * 512;
        const unsigned short* base1 = Wpk + (size_t)((cg * 2 + 1) * KC_N) * 512;
        #pragma unroll
        for (int i = 0; i < 12; ++i) {
            int kc = (i < 4) ? (ks * 4 + i) : (16 + ks * 8 + (i - 4));
            Bf0[i] = *reinterpret_cast<const s16x8*>(base0 + ((size_t)kc * 64 + l) * 8);
            Bf1[i] = *reinterpret_cast<const s16x8*>(base1 + ((size_t)kc * 64 + l) * 8);
        }
        #pragma unroll
        for (int i = 0; i < 12; ++i)
            asm volatile("" : "+v"(Bf0[i]), "+v"(Bf1[i]));   // liveness pin
    }

    // ---- epilogue thread state (tid<256): thread -> (batch b_l, hidden unit u) ----
    const int b_l = tid >> 3, u = tid & 7;
    const int brow = b0g + b_l;
    const int jcol = cg * 8 + u;
    float c_reg = 0.f, h_reg = 0.f;
    float4 bias = make_float4(0.f, 0.f, 0.f, 0.f);
    if (tid < 256) {
        c_reg = c0[jcol];
        h_reg = h0[jcol];
        bias = *reinterpret_cast<const float4*>(bias_p + cg * 32 + u * 4);
    }

    // poll set: rowgrps {2mi, 2mi+1} x 128 blocks = 256 dwords; 4/lane
    const unsigned int* fpoll = flags + mh * 512 + mi * 256 + l * 4;
    unsigned int* fstore = flags + mh * 512 + w * 128 + cg;    // used by w<4 only
    const float* xbase = x + (size_t)arow * T_ * D_ + ks * 128 + quad * 8;

    #pragma unroll 1
    for (int t = 0; t < T_; ++t) {
        const unsigned short* hin  = hbuf + (size_t)(t & 1) * (B_ * H_);
        unsigned short*       hout = hbuf + (size_t)((t + 1) & 1) * (B_ * H_);

        // ---- phase A: x-part MFMA (no h dependency) + mask prefetch ----
        f32x4 a0 = {0.f, 0.f, 0.f, 0.f}, a1 = {0.f, 0.f, 0.f, 0.f};
        const float* xp = xbase + (size_t)t * D_;
        int mv = 0;
        if (tid < 256) mv = mask[(size_t)brow * T_ + t];
        #pragma unroll
        for (int i = 0; i < 4; ++i) {
            float4 v0 = *reinterpret_cast<const float4*>(xp + i * 32);
            float4 v1 = *reinterpret_cast<const float4*>(xp + i * 32 + 4);
            s16x8 af = cvt8(v0, v1);
            a0 = __builtin_amdgcn_mfma_f32_16x16x32_bf16(af, Bf0[i], a0, 0, 0, 0);
            a1 = __builtin_amdgcn_mfma_f32_16x16x32_bf16(af, Bf1[i], a1, 0, 0, 0);
        }

        // ---- per-wave thin poll: my 16 rows' producer flags (256 dwords) ----
        if (t > 0) {
            const unsigned int tgt = (unsigned int)t;
            int guard = 0;
            for (;;) {
                unsigned int f0 = __hip_atomic_load(fpoll + 0, __ATOMIC_RELAXED, __HIP_MEMORY_SCOPE_AGENT);
                unsigned int f1 = __hip_atomic_load(fpoll + 1, __ATOMIC_RELAXED, __HIP_MEMORY_SCOPE_AGENT);
                unsigned int f2 = __hip_atomic_load(fpoll + 2, __ATOMIC_RELAXED, __HIP_MEMORY_SCOPE_AGENT);
                unsigned int f3 = __hip_atomic_load(fpoll + 3, __ATOMIC_RELAXED, __HIP_MEMORY_SCOPE_AGENT);
                int ok = (int)((f0 >= tgt) & (f1 >= tgt) & (f2 >= tgt) & (f3 >= tgt));
                if (__all(ok)) break;
                if (++guard > (1 << 16)) break;   // hard bail: never hang
                __builtin_amdgcn_s_sleep(1);
            }
        }
        __builtin_amdgcn_fence(__ATOMIC_ACQUIRE, "workgroup");   // compiler ordering only

        // ---- phase B: h-part — issue ALL 16 coherent loads, then MFMA chain ----
        const unsigned short* hrow = hin + (size_t)arow * H_ + ks * 256 + quad * 8;
        s16x8 hf[8];
        #pragma unroll
        for (int i = 0; i < 8; ++i) {
            const unsigned long long* hp =
                reinterpret_cast<const unsigned long long*>(hrow + i * 32);
            union { s16x8 v; unsigned long long q[2]; } au;
            au.q[0] = __hip_atomic_load(hp,     __ATOMIC_RELAXED, __HIP_MEMORY_SCOPE_AGENT);
            au.q[1] = __hip_atomic_load(hp + 1, __ATOMIC_RELAXED, __HIP_MEMORY_SCOPE_AGENT);
            hf[i] = au.v;
        }
        #pragma unroll
        for (int i = 0; i < 8; ++i) {
            a0 = __builtin_amdgcn_mfma_f32_16x16x32_bf16(hf[i], Bf0[4 + i], a0, 0, 0, 0);
            a1 = __builtin_amdgcn_mfma_f32_16x16x32_bf16(hf[i], Bf1[4 + i], a1, 0, 0, 0);
        }
        // C/D layout: col = lane&15, row = quad*4 + reg (m89-verified)
        #pragma unroll
        for (int r = 0; r < 4; ++r) {
            Dls[ks][mi * 16 + quad * 4 + r][l15]      = a0[r];
            Dls[ks][mi * 16 + quad * 4 + r][16 + l15] = a1[r];
        }
        __syncthreads();   // the ONLY block barrier per step (Dls -> epilogue)

        // ---- epilogue (waves 0-3): reduce, LSTM cell, h store, OWN-wave flag ----
        if (tid < 256) {
            f32x4 s0 = *reinterpret_cast<f32x4*>(&Dls[0][b_l][u * 4]);
            f32x4 s1 = *reinterpret_cast<f32x4*>(&Dls[1][b_l][u * 4]);
            f32x4 s2 = *reinterpret_cast<f32x4*>(&Dls[2][b_l][u * 4]);
            f32x4 s3 = *reinterpret_cast<f32x4*>(&Dls[3][b_l][u * 4]);
            f32x4 g = s0 + s1 + s2 + s3;
            float gi = sigm  (g[0] + bias.x);
            float gf = sigm  (g[1] + bias.y);
            float gg = tanh_f(g[2] + bias.z);
            float go = sigm  (g[3] + bias.w);
            float c_new = gf * c_reg + gi * gg;
            float h_new = go * tanh_f(c_new);
            float h2 = mv ? h_new : h_reg;
            c_reg = mv ? c_new : c_reg;
            h_reg = h2;
            if (t < T_ - 1) {
                // pair adjacent units into one dword, store coherently (sc1)
                unsigned int hv = (unsigned int)f2bf(h2);
                unsigned int hx = (unsigned int)__shfl_xor((int)hv, 1);
                if ((u & 1) == 0) {
                    unsigned int pk = (hx << 16) | hv;
                    __hip_atomic_store(reinterpret_cast<unsigned int*>(
                                           hout + (size_t)brow * H_ + jcol),
                                       pk, __ATOMIC_RELAXED, __HIP_MEMORY_SCOPE_AGENT);
                }
                // wave-local drain: only THIS wave's h-store ACKs, no block barrier
                asm volatile("s_waitcnt vmcnt(0)" ::: "memory");
                if (l == 0)
                    __hip_atomic_store(fstore, (unsigned int)(t + 1),
                                       __ATOMIC_RELAXED, __HIP_MEMORY_SCOPE_AGENT);
            }
            out[((size_t)brow * T_ + t) * H_ + jcol] = h2;   // off critical path
        }
        // waves 4-7 skip epilogue entirely and start phase A of t+1 immediately
    }
}

extern "C" void kernel_launch(void* const* d_in, const int* in_sizes, int n_in,
                              void* d_out, int out_size, void* d_ws, size_t ws_size,
                              hipStream_t stream)
{
    const float* x    = (const float*)d_in[0];
    const int*   mask = (const int*)d_in[1];
    const float* W_ih = (const float*)d_in[2];
    const float* W_hh = (const float*)d_in[3];
    const float* b_ih = (const float*)d_in[4];
    const float* b_hh = (const float*)d_in[5];
    const float* h0   = (const float*)d_in[6];
    const float* c0   = (const float*)d_in[7];
    float* out = (float*)d_out;

    // ws layout (~12.9 MB total)
    char* wsb = (char*)d_ws;
    unsigned short* Wpk    = (unsigned short*)(wsb);             // 12,582,912 B
    float*          bias_p = (float*)(wsb + 12582912);           //     16,384 B
    unsigned short* hbuf   = (unsigned short*)(wsb + 12599296);  //    262,144 B (2 parities)
    unsigned int*   flags  = (unsigned int*)(wsb + 12861440);    //      4,096 B

    // inputs re-poisoned every call -> re-pack every call
    pack_w<<<24576, 256, 0, stream>>>(W_ih, W_hh, Wpk);
    init_state2<<<256, 256, 0, stream>>>(h0, b_ih, b_hh, hbuf, bias_p, flags);
    lstm_persist<<<256, 512, 0, stream>>>(x, mask, Wpk, bias_p, h0, c0, hbuf, out, flags);
}